// Round 16
// baseline (66.407 us; speedup 1.0000x reference)
//
#include <hip/hip_runtime.h>

#define NB 64
#define NT 1024
#define NA 512
#define NF 32
#define KW 31
#define PADW 15
#define TC 64                      // t's per block
#define CWN (2 * KW * NF)          // 1984 floats of transposed conv weights
#define UPART_OFF 34816L           // word offset of upart in ws (256B-aligned)

typedef __fp16 half2v __attribute__((ext_vector_type(2)));

__device__ __forceinline__ float fast_tanh(float x) {
    float e = __builtin_amdgcn_exp2f(x * 2.885390081777927f);
    return 1.0f - 2.0f * __builtin_amdgcn_rcpf(1.0f + e);
}
__device__ __forceinline__ float fast_sigmoid(float u) {
    return __builtin_amdgcn_rcpf(1.0f + __builtin_amdgcn_exp2f(-u * 1.4426950408889634f));
}
__device__ __forceinline__ unsigned pkrtz(float a, float b) {
    half2v h = __builtin_amdgcn_cvt_pkrtz(a, b);
    return __builtin_bit_cast(unsigned, h);
}
__device__ __forceinline__ float fdot2u(unsigned cv, unsigned lw, float acc) {
#if __has_builtin(__builtin_amdgcn_fdot2)
    return __builtin_amdgcn_fdot2(__builtin_bit_cast(half2v, cv),
                                  __builtin_bit_cast(half2v, lw), acc, false);
#else
    half2v a = __builtin_bit_cast(half2v, cv), b = __builtin_bit_cast(half2v, lw);
    return acc + (float)a.x * (float)b.x + (float)a.y * (float)b.y;
#endif
}

// ---------------- kernel A: pq = query @ W_w^T + W_b (coalesced row-per-wave GEMV)
__global__ __launch_bounds__(256) void lsa_pq(
    const float* __restrict__ query, const float* __restrict__ Ww,
    const float* __restrict__ Wb, const float* __restrict__ convw,
    float* __restrict__ pq, float* __restrict__ cwT)
{
    if (blockIdx.x == 0) {
        for (int i = threadIdx.x; i < NF * 2 * KW; i += 256) {
            int f = i / (2 * KW);
            int r = i - f * 2 * KW;
            int c = r / KW;
            int k = r - c * KW;
            cwT[(c * KW + k) * NF + f] = convw[i];   // [c][k][f]
        }
    }
    __shared__ float qs[NA];
    int tid  = threadIdx.x;
    int lane = tid & 63;
    int wv   = tid >> 6;
    int b     = blockIdx.x >> 3;
    int chunk = blockIdx.x & 7;
    qs[tid]       = query[b * NA + tid];
    qs[tid + 256] = query[b * NA + tid + 256];
    __syncthreads();

    float4 q0 = *(const float4*)(qs + 8 * lane);
    float4 q1 = *(const float4*)(qs + 8 * lane + 4);
#pragma unroll 4
    for (int i = 0; i < 16; ++i) {
        int a = chunk * 64 + wv * 16 + i;
        const float4* wr = (const float4*)(Ww + (long)a * NA + 8 * lane);
        float4 w0 = wr[0], w1 = wr[1];
        float s = w0.x * q0.x + w0.y * q0.y + w0.z * q0.z + w0.w * q0.w
                + w1.x * q1.x + w1.y * q1.y + w1.z * q1.z + w1.w * q1.w;
#pragma unroll
        for (int m = 1; m <= 32; m <<= 1) s += __shfl_xor(s, m, 64);
        if (lane == 0) pq[b * NA + a] = s + Wb[a];
    }
}

// ---------------- kernel B (hot): partial u -> upart[ah][b][t]
// 2048 blocks = (b, 16 t-chunks, 2 a-halves). Thread owns ONE a for 64 t's.
// VGPR target <= 64 -> 8 waves/SIMD (the occupancy experiment).
__global__ __launch_bounds__(256, 8) void lsa_main(
    const float* __restrict__ enc, const float* __restrict__ cum,
    const float* __restrict__ att, const float* __restrict__ cwT,
    const float* __restrict__ Lw, const float* __restrict__ Lb,
    const float* __restrict__ vw, const float* __restrict__ pq,
    float* __restrict__ upart)
{
    __shared__ float cw_s[CWN];            // conv weights [c][k][f], 7.75 KB
    __shared__ float cum_s[TC + 30];
    __shared__ float att_s[TC + 30];
    __shared__ unsigned cvsh[TC][20];      // f16x2 conv output, 80B row stride
    __shared__ float wred[4][TC + 2];      // per-wave tt sums

    int tid  = threadIdx.x;
    int lane = tid & 63;
    int wv   = tid >> 6;
    int bid  = blockIdx.x;
    int b    = bid >> 5;
    int t0   = ((bid >> 1) & 15) * TC;
    int ah   = bid & 1;
    int a    = ah * 256 + tid;

    // ---- stage conv weights into LDS (coalesced float4 copy)
    {
        const float4* src = (const float4*)cwT;
        float4* dst = (float4*)cw_s;
        if (tid < 248) {
            dst[tid]       = src[tid];
            dst[tid + 248] = src[tid + 248];
        }
    }
    // ---- stage cum/att slice (with halo)
    if (tid < TC + 30) {
        int t = t0 - PADW + tid;
        bool ok = (t >= 0) && (t < NT);
        cum_s[tid] = ok ? cum[b * NT + t] : 0.f;
        att_s[tid] = ok ? att[b * NT + t] : 0.f;
    }

    // ---- per-thread constants: ONE L_w row as f16x2 (16 regs)
    const float4* lp = (const float4*)(Lw + (long)a * NF);
    unsigned h[16];
#pragma unroll
    for (int i = 0; i < 8; ++i) {
        float4 w = lp[i];
        h[2 * i]     = pkrtz(w.x, w.y);
        h[2 * i + 1] = pkrtz(w.z, w.w);
    }
    float c = pq[b * NA + a] + Lb[a];
    float v = vw[a];
    __syncthreads();

    // ---- conv phase: wave wv computes filters [8wv, 8wv+8) for tt = lane (all 64)
    {
        int tt  = lane;
        int fbu = wv * 8;
        float acc[8] = {0, 0, 0, 0, 0, 0, 0, 0};
#pragma unroll
        for (int k = 0; k < KW; ++k) {
            float x0 = cum_s[tt + k];
            float x1 = att_s[tt + k];
            const float4* A  = (const float4*)(cw_s + k * NF + fbu);
            const float4* Bv = (const float4*)(cw_s + (KW + k) * NF + fbu);
#pragma unroll
            for (int j = 0; j < 2; ++j) {
                float4 wa = A[j], wb = Bv[j];
                acc[4 * j + 0] = fmaf(x0, wa.x, fmaf(x1, wb.x, acc[4 * j + 0]));
                acc[4 * j + 1] = fmaf(x0, wa.y, fmaf(x1, wb.y, acc[4 * j + 1]));
                acc[4 * j + 2] = fmaf(x0, wa.z, fmaf(x1, wb.z, acc[4 * j + 2]));
                acc[4 * j + 3] = fmaf(x0, wa.w, fmaf(x1, wb.w, acc[4 * j + 3]));
            }
        }
        uint4 pk;
        pk.x = pkrtz(acc[0], acc[1]);
        pk.y = pkrtz(acc[2], acc[3]);
        pk.z = pkrtz(acc[4], acc[5]);
        pk.w = pkrtz(acc[6], acc[7]);
        *(uint4*)&cvsh[tt][wv * 4] = pk;
    }
    __syncthreads();

    // ---- main loop: 8 passes of 8 tt; ONE a per thread (16 fdot2/tt)
    const float* ecol = enc + ((long)b * NT + t0) * NA + a;
#pragma unroll 1
    for (int pass = 0; pass < 8; ++pass) {
        float p[8];
#pragma unroll
        for (int j = 0; j < 8; ++j) {
            int gtt = pass * 8 + j;
            float e = ecol[(long)gtt * NA];
            uint4 ca = *(const uint4*)&cvsh[gtt][0];
            uint4 cb = *(const uint4*)&cvsh[gtt][4];
            uint4 cc = *(const uint4*)&cvsh[gtt][8];
            uint4 cd = *(const uint4*)&cvsh[gtt][12];
            float x0 = 0.f, x1 = 0.f;
            x0 = fdot2u(ca.x, h[0],  x0); x1 = fdot2u(ca.y, h[1],  x1);
            x0 = fdot2u(ca.z, h[2],  x0); x1 = fdot2u(ca.w, h[3],  x1);
            x0 = fdot2u(cb.x, h[4],  x0); x1 = fdot2u(cb.y, h[5],  x1);
            x0 = fdot2u(cb.z, h[6],  x0); x1 = fdot2u(cb.w, h[7],  x1);
            x0 = fdot2u(cc.x, h[8],  x0); x1 = fdot2u(cc.y, h[9],  x1);
            x0 = fdot2u(cc.z, h[10], x0); x1 = fdot2u(cc.w, h[11], x1);
            x0 = fdot2u(cd.x, h[12], x0); x1 = fdot2u(cd.y, h[13], x1);
            x0 = fdot2u(cd.z, h[14], x0); x1 = fdot2u(cd.w, h[15], x1);
            p[j] = fast_tanh(x0 + x1 + c + e) * v;
        }

        // butterfly transpose-reduce over 8 tt (lane bits 0..2), then octets
        {
            int len = 8;
#pragma unroll
            for (int m = 1; m <= 4; m <<= 1) {
                int hlen = len >> 1;
                bool up = (lane & m) != 0;
#pragma unroll
                for (int i = 0; i < 4; ++i) {
                    if (i < hlen) {
                        float send = up ? p[i] : p[i + hlen];
                        float keep = up ? p[i + hlen] : p[i];
                        p[i] = keep + __shfl_xor(send, m, 64);
                    }
                }
                len = hlen;
            }
            float s = p[0];
            s += __shfl_xor(s, 8, 64);
            s += __shfl_xor(s, 16, 64);
            s += __shfl_xor(s, 32, 64);
            int l3 = lane & 7;
            int tt = ((l3 & 1) << 2) | (l3 & 2) | ((l3 & 4) >> 2);
            if (lane < 8) wred[wv][pass * 8 + tt] = s;
        }
    }
    __syncthreads();
    if (tid < TC) {
        float u = wred[0][tid] + wred[1][tid] + wred[2][tid] + wred[3][tid];
        upart[((long)ah * NB + b) * NT + t0 + tid] = u;
    }
}

// ---------------- kernel C: sigmoid + alpha recursion + mask + normalize
__global__ __launch_bounds__(256) void lsa_norm(
    const float* __restrict__ alpha, const int* __restrict__ plen,
    const float* __restrict__ upart, float* __restrict__ out)
{
    __shared__ float red[4];
    int tid = threadIdx.x;
    int b = blockIdx.x;
    int pl = plen[b];
    float w[4];
    float psum = 0.f;
#pragma unroll
    for (int j = 0; j < 4; ++j) {
        int t = tid + 256 * j;
        float u = upart[(long)b * NT + t] + upart[((long)NB + b) * NT + t];
        float s = fast_sigmoid(u);
        float al  = alpha[b * NT + t];
        float am1 = (t >= 1) ? alpha[b * NT + t - 1] : 0.f;
        float am2 = (t >= 2) ? alpha[b * NT + t - 2] : 0.f;
        float val = (t < pl) ? (al + am1 + am2 + 1e-7f) * s : 0.f;
        w[j] = val;
        psum += val;
    }
#pragma unroll
    for (int m = 32; m >= 1; m >>= 1) psum += __shfl_xor(psum, m, 64);
    int lane = tid & 63, wid = tid >> 6;
    if (lane == 0) red[wid] = psum;
    __syncthreads();
    float total = red[0] + red[1] + red[2] + red[3];
    float inv = 1.0f / total;
#pragma unroll
    for (int j = 0; j < 4; ++j) {
        int t = tid + 256 * j;
        out[b * NT + t] = w[j] * inv;
    }
}

extern "C" void kernel_launch(void* const* d_in, const int* in_sizes, int n_in,
                              void* d_out, int out_size, void* d_ws, size_t ws_size,
                              hipStream_t stream)
{
    const float* enc   = (const float*)d_in[0];
    const float* query = (const float*)d_in[1];
    const float* cum   = (const float*)d_in[2];
    const float* att   = (const float*)d_in[3];
    const float* alpha = (const float*)d_in[4];
    const float* convw = (const float*)d_in[5];
    const float* Lw    = (const float*)d_in[6];
    const float* Lb    = (const float*)d_in[7];
    const float* Ww    = (const float*)d_in[8];
    const float* Wb    = (const float*)d_in[9];
    const float* vw    = (const float*)d_in[10];
    const int*   plen  = (const int*)d_in[12];

    float* pq    = (float*)d_ws;                     // 32768 floats
    float* cwT   = (float*)d_ws + NB * NA;           // 1984 floats
    float* upart = (float*)d_ws + UPART_OFF;         // 2*64*1024 floats = 512 KB
    float* sout  = (float*)d_out;

    lsa_pq  <<<NB * 8,  256, 0, stream>>>(query, Ww, Wb, convw, pq, cwT);
    lsa_main<<<NB * 32, 256, 0, stream>>>(enc, cum, att, cwT, Lw, Lb, vw, pq, upart);
    lsa_norm<<<NB,      256, 0, stream>>>(alpha, plen, upart, sout);
}

// Round 17
// 57.001 us; speedup vs baseline: 1.1650x; 1.1650x over previous
//
#include <hip/hip_runtime.h>

#define NB 64
#define NT 1024
#define NA 512
#define NF 32
#define KW 31
#define PADW 15
#define TC 64                      // t's per block
#define CWN (2 * KW * NF)          // 1984 floats of transposed conv weights

typedef __fp16 half2v __attribute__((ext_vector_type(2)));

__device__ __forceinline__ float fast_tanh(float x) {
    float e = __builtin_amdgcn_exp2f(x * 2.885390081777927f);
    return 1.0f - 2.0f * __builtin_amdgcn_rcpf(1.0f + e);
}
__device__ __forceinline__ float fast_sigmoid(float u) {
    return __builtin_amdgcn_rcpf(1.0f + __builtin_amdgcn_exp2f(-u * 1.4426950408889634f));
}
__device__ __forceinline__ unsigned pkrtz(float a, float b) {
    half2v h = __builtin_amdgcn_cvt_pkrtz(a, b);
    return __builtin_bit_cast(unsigned, h);
}
__device__ __forceinline__ float fdot2u(unsigned cv, unsigned lw, float acc) {
#if __has_builtin(__builtin_amdgcn_fdot2)
    return __builtin_amdgcn_fdot2(__builtin_bit_cast(half2v, cv),
                                  __builtin_bit_cast(half2v, lw), acc, false);
#else
    half2v a = __builtin_bit_cast(half2v, cv), b = __builtin_bit_cast(half2v, lw);
    return acc + (float)a.x * (float)b.x + (float)a.y * (float)b.y;
#endif
}

// ---------------- kernel A: pq = query @ W_w^T + W_b (coalesced row-per-wave GEMV)
// grid = NB * 8 blocks; block = (b, 64-a chunk); wave owns 16 rows.
// Lane l reads Ww[a][8l..8l+7] -> the wave reads the full contiguous 2 KB row.
__global__ __launch_bounds__(256) void lsa_pq(
    const float* __restrict__ query, const float* __restrict__ Ww,
    const float* __restrict__ Wb, const float* __restrict__ convw,
    float* __restrict__ pq, float* __restrict__ cwT)
{
    if (blockIdx.x == 0) {
        for (int i = threadIdx.x; i < NF * 2 * KW; i += 256) {
            int f = i / (2 * KW);
            int r = i - f * 2 * KW;
            int c = r / KW;
            int k = r - c * KW;
            cwT[(c * KW + k) * NF + f] = convw[i];   // [c][k][f]
        }
    }
    __shared__ float qs[NA];
    int tid  = threadIdx.x;
    int lane = tid & 63;
    int wv   = tid >> 6;
    int b     = blockIdx.x >> 3;
    int chunk = blockIdx.x & 7;
    qs[tid]       = query[b * NA + tid];
    qs[tid + 256] = query[b * NA + tid + 256];
    __syncthreads();

    float4 q0 = *(const float4*)(qs + 8 * lane);
    float4 q1 = *(const float4*)(qs + 8 * lane + 4);
#pragma unroll 4
    for (int i = 0; i < 16; ++i) {
        int a = chunk * 64 + wv * 16 + i;
        const float4* wr = (const float4*)(Ww + (long)a * NA + 8 * lane);
        float4 w0 = wr[0], w1 = wr[1];
        float s = w0.x * q0.x + w0.y * q0.y + w0.z * q0.z + w0.w * q0.w
                + w1.x * q1.x + w1.y * q1.y + w1.z * q1.z + w1.w * q1.w;
#pragma unroll
        for (int m = 1; m <= 32; m <<= 1) s += __shfl_xor(s, m, 64);
        if (lane == 0) pq[b * NA + a] = s + Wb[a];
    }
}

// ---------------- kernel B (hot): s = sigmoid(u) -> d_out
// 1024 blocks = 4/CU fully resident. Thread owns a = 2*tid, 2*tid+1 for 64 t's.
__global__ __launch_bounds__(256, 4) void lsa_main(
    const float* __restrict__ enc, const float* __restrict__ cum,
    const float* __restrict__ att, const float* __restrict__ cwT,
    const float* __restrict__ Lw, const float* __restrict__ Lb,
    const float* __restrict__ vw, const float* __restrict__ pq,
    float* __restrict__ sout)
{
    __shared__ float cw_s[CWN];            // conv weights [c][k][f], 7.75 KB
    __shared__ float cum_s[TC + 30];
    __shared__ float att_s[TC + 30];
    __shared__ unsigned cvsh[TC][20];      // f16x2 conv output, 80B row stride
    __shared__ float wred[4][TC + 2];      // per-wave tt sums

    int tid  = threadIdx.x;
    int lane = tid & 63;
    int wv   = tid >> 6;
    int b    = blockIdx.x >> 4;            // NT/TC = 16 chunks
    int t0   = (blockIdx.x & 15) * TC;

    // ---- stage conv weights into LDS (coalesced float4 copy)
    {
        const float4* src = (const float4*)cwT;
        float4* dst = (float4*)cw_s;
        if (tid < 248) {                   // 496 float4 total
            dst[tid]       = src[tid];
            dst[tid + 248] = src[tid + 248];
        }
    }
    // ---- stage cum/att slice (with halo)
    if (tid < TC + 30) {
        int t = t0 - PADW + tid;
        bool ok = (t >= 0) && (t < NT);
        cum_s[tid] = ok ? cum[b * NT + t] : 0.f;
        att_s[tid] = ok ? att[b * NT + t] : 0.f;
    }

    // ---- per-thread constants: pack L_w rows to f16x2 as they arrive
    int a0 = 2 * tid;
    const float4* lp = (const float4*)(Lw + (long)a0 * NF);
    unsigned h0[16], h1[16];
#pragma unroll
    for (int i = 0; i < 8; ++i) {
        float4 wa = lp[i];
        float4 wb = lp[8 + i];
        h0[2 * i]     = pkrtz(wa.x, wa.y);
        h0[2 * i + 1] = pkrtz(wa.z, wa.w);
        h1[2 * i]     = pkrtz(wb.x, wb.y);
        h1[2 * i + 1] = pkrtz(wb.z, wb.w);
    }
    float c0 = pq[b * NA + a0]     + Lb[a0];
    float c1 = pq[b * NA + a0 + 1] + Lb[a0 + 1];
    float vx = vw[a0], vy = vw[a0 + 1];
    __syncthreads();

    // ---- conv phase: wave wv computes filters [8wv, 8wv+8) for tt = lane (all 64)
    {
        int tt  = lane;
        int fbu = wv * 8;
        float acc[8] = {0, 0, 0, 0, 0, 0, 0, 0};
#pragma unroll
        for (int k = 0; k < KW; ++k) {
            float x0 = cum_s[tt + k];
            float x1 = att_s[tt + k];
            const float4* A  = (const float4*)(cw_s + k * NF + fbu);
            const float4* Bv = (const float4*)(cw_s + (KW + k) * NF + fbu);
#pragma unroll
            for (int j = 0; j < 2; ++j) {
                float4 wa = A[j], wb = Bv[j];
                acc[4 * j + 0] = fmaf(x0, wa.x, fmaf(x1, wb.x, acc[4 * j + 0]));
                acc[4 * j + 1] = fmaf(x0, wa.y, fmaf(x1, wb.y, acc[4 * j + 1]));
                acc[4 * j + 2] = fmaf(x0, wa.z, fmaf(x1, wb.z, acc[4 * j + 2]));
                acc[4 * j + 3] = fmaf(x0, wa.w, fmaf(x1, wb.w, acc[4 * j + 3]));
            }
        }
        uint4 pk;
        pk.x = pkrtz(acc[0], acc[1]);
        pk.y = pkrtz(acc[2], acc[3]);
        pk.z = pkrtz(acc[4], acc[5]);
        pk.w = pkrtz(acc[6], acc[7]);
        *(uint4*)&cvsh[tt][wv * 4] = pk;
    }
    __syncthreads();

    // ---- main loop: two passes of 32 tt; per-thread 2 a's; f16 dot2
    const float* erow = enc + ((long)b * NT + t0) * NA + a0;
#pragma unroll 1
    for (int half = 0; half < 2; ++half) {
        float p32[32];
#pragma unroll
        for (int tt = 0; tt < 32; ++tt) {
            int gtt = half * 32 + tt;
            float2 e = *(const float2*)(erow + (long)gtt * NA);
            float x0[2] = {c0 + e.x, 0.f};
            float x1[2] = {c1 + e.y, 0.f};
#pragma unroll
            for (int q = 0; q < 4; ++q) {
                uint4 cv = *(const uint4*)&cvsh[gtt][4 * q];
                int p = q & 1;
                x0[p] = fdot2u(cv.x, h0[4 * q + 0], x0[p]);
                x0[p] = fdot2u(cv.y, h0[4 * q + 1], x0[p]);
                x0[p] = fdot2u(cv.z, h0[4 * q + 2], x0[p]);
                x0[p] = fdot2u(cv.w, h0[4 * q + 3], x0[p]);
                x1[p] = fdot2u(cv.x, h1[4 * q + 0], x1[p]);
                x1[p] = fdot2u(cv.y, h1[4 * q + 1], x1[p]);
                x1[p] = fdot2u(cv.z, h1[4 * q + 2], x1[p]);
                x1[p] = fdot2u(cv.w, h1[4 * q + 3], x1[p]);
            }
            p32[tt] = fast_tanh(x0[0] + x0[1]) * vx + fast_tanh(x1[0] + x1[1]) * vy;
        }

        // register butterfly transpose-reduce across lane bits 0..4
        {
            int len = 32;
#pragma unroll
            for (int m = 1; m <= 16; m <<= 1) {
                int hlen = len >> 1;
                bool up = (lane & m) != 0;
#pragma unroll
                for (int i = 0; i < 16; ++i) {
                    if (i < hlen) {
                        float send = up ? p32[i] : p32[i + hlen];
                        float keep = up ? p32[i + hlen] : p32[i];
                        p32[i] = keep + __shfl_xor(send, m, 64);
                    }
                }
                len = hlen;
            }
            float v = p32[0] + __shfl_xor(p32[0], 32, 64);
            int l = lane & 31;
            int tt = ((l & 1) << 4) | ((l & 2) << 2) | (l & 4) | ((l & 8) >> 2) | ((l & 16) >> 4);
            if (lane < 32) wred[wv][half * 32 + tt] = v;
        }
    }
    __syncthreads();
    if (tid < TC) {
        float u = wred[0][tid] + wred[1][tid] + wred[2][tid] + wred[3][tid];
        sout[b * NT + t0 + tid] = fast_sigmoid(u);
    }
}

// ---------------- kernel C: normalize with alpha recursion + mask (in place)
__global__ __launch_bounds__(256) void lsa_norm(
    const float* __restrict__ alpha, const int* __restrict__ plen,
    float* __restrict__ out)
{
    __shared__ float red[4];
    int tid = threadIdx.x;
    int b = blockIdx.x;
    int pl = plen[b];
    float w[4];
    float psum = 0.f;
#pragma unroll
    for (int j = 0; j < 4; ++j) {
        int t = tid + 256 * j;
        float s   = out[b * NT + t];
        float al  = alpha[b * NT + t];
        float am1 = (t >= 1) ? alpha[b * NT + t - 1] : 0.f;
        float am2 = (t >= 2) ? alpha[b * NT + t - 2] : 0.f;
        float val = (t < pl) ? (al + am1 + am2 + 1e-7f) * s : 0.f;
        w[j] = val;
        psum += val;
    }
#pragma unroll
    for (int m = 32; m >= 1; m >>= 1) psum += __shfl_xor(psum, m, 64);
    int lane = tid & 63, wid = tid >> 6;
    if (lane == 0) red[wid] = psum;
    __syncthreads();
    float total = red[0] + red[1] + red[2] + red[3];
    float inv = 1.0f / total;
#pragma unroll
    for (int j = 0; j < 4; ++j) {
        int t = tid + 256 * j;
        out[b * NT + t] = w[j] * inv;
    }
}

extern "C" void kernel_launch(void* const* d_in, const int* in_sizes, int n_in,
                              void* d_out, int out_size, void* d_ws, size_t ws_size,
                              hipStream_t stream)
{
    const float* enc   = (const float*)d_in[0];
    const float* query = (const float*)d_in[1];
    const float* cum   = (const float*)d_in[2];
    const float* att   = (const float*)d_in[3];
    const float* alpha = (const float*)d_in[4];
    const float* convw = (const float*)d_in[5];
    const float* Lw    = (const float*)d_in[6];
    const float* Lb    = (const float*)d_in[7];
    const float* Ww    = (const float*)d_in[8];
    const float* Wb    = (const float*)d_in[9];
    const float* vw    = (const float*)d_in[10];
    const int*   plen  = (const int*)d_in[12];

    float* pq  = (float*)d_ws;                       // 64*512 floats = 128 KB
    float* cwT = (float*)d_ws + NB * NA;             // 1984 floats
    float* sout = (float*)d_out;

    lsa_pq  <<<NB * 8,         256, 0, stream>>>(query, Ww, Wb, convw, pq, cwT);
    lsa_main<<<NB * (NT / TC), 256, 0, stream>>>(enc, cum, att, cwT, Lw, Lb, vw, pq, sout);
    lsa_norm<<<NB,             256, 0, stream>>>(alpha, plen, sout);
}